// Round 17
// baseline (364.104 us; speedup 1.0000x reference)
//
#include <hip/hip_runtime.h>

// ---------------------------------------------------------------------------
// BlockGNN on MI355X, round 19: slice-major u layout.
//   - uA stored [4][N][64B] (slice-major): each slice = contiguous 3.2MB,
//     FITS the 4MB per-XCD L2 (r16's interleaved 128B slices had 6.4MB
//     footprint -> capacity misses, FETCH 61MB). slice=blockIdx&3 -> 2 XCDs
//     per slice -> compulsory fetch ~26MB. No line straddle (2 nodes/line,
//     both resident).
//   - u_x stored [2][N][64B] (layer-0's 6.4MB footprint also exceeded L2).
//   - GEMM OUTMODE1 writes uA slice-major; fill_prep writes u_x slice-major;
//     aggA stays row-major (GEMM A reads unchanged).
//   - everything else: r18 composition (347.6us verified, absmax 0.015625).
// ---------------------------------------------------------------------------

typedef float f32x4 __attribute__((ext_vector_type(4)));
typedef float f32x2 __attribute__((ext_vector_type(2)));

__device__ inline float bf2f(unsigned short u) {
  union { unsigned int i; float f; } v;
  v.i = (unsigned int)u << 16;
  return v.f;
}
__device__ inline unsigned short f2bf(float f) {
  union { unsigned int i; float f; } v;
  v.f = f;
  unsigned int i = v.i;
  return (unsigned short)((i + 0x7fffu + ((i >> 16) & 1u)) >> 16);  // RNE
}
// fp8 e4m3 pack of 4 floats -> dword (bytes 0..3)
__device__ inline unsigned pack4_fp8(float a, float b, float c, float d) {
  int r = 0;
  r = __builtin_amdgcn_cvt_pk_fp8_f32(a, b, r, false);
  r = __builtin_amdgcn_cvt_pk_fp8_f32(c, d, r, true);
  return (unsigned)r;
}
__device__ inline unsigned char f2fp8(float v) {
  return (unsigned char)((unsigned)__builtin_amdgcn_cvt_pk_fp8_f32(v, v, 0, false) & 0xffu);
}
// accumulate 16 fp8 channels (one uint4) into acc[16]; msk==0 squashes (+0.0)
__device__ inline void acc16_fp8(float* acc, uint4 r, unsigned msk) {
  unsigned w[4] = {r.x, r.y, r.z, r.w};
#pragma unroll
  for (int d = 0; d < 4; ++d) {
    int v = (int)(w[d] & msk);
    f32x2 lo = __builtin_amdgcn_cvt_pk_f32_fp8(v, false);
    f32x2 hi = __builtin_amdgcn_cvt_pk_f32_fp8(v, true);
    acc[4 * d + 0] += lo[0];
    acc[4 * d + 1] += lo[1];
    acc[4 * d + 2] += hi[0];
    acc[4 * d + 3] += hi[1];
  }
}
__device__ inline int lbound(const int* a, int n, int key) {
  int lo = 0, hi = n;
  while (lo < hi) {
    int mid = (lo + hi) >> 1;
    if (a[mid] < key) lo = mid + 1; else hi = mid;
  }
  return lo;
}

// ----------------------------- CSR build -----------------------------------

// counting pass that also records each edge's slot (atomicAdd return value).
// 4 edges/thread: int4 dst read, uchar4 pos write (max deg ~45 << 255).
__global__ void count_pos_kernel(const int* __restrict__ dst, int* __restrict__ deg,
                                 unsigned char* __restrict__ pos, int E) {
  int t = blockIdx.x * blockDim.x + threadIdx.x;
  int e = t * 4;
  if (e + 3 < E) {
    int4 d4 = *(const int4*)&dst[e];
    uchar4 p4;
    p4.x = (unsigned char)atomicAdd(&deg[d4.x], 1);
    p4.y = (unsigned char)atomicAdd(&deg[d4.y], 1);
    p4.z = (unsigned char)atomicAdd(&deg[d4.z], 1);
    p4.w = (unsigned char)atomicAdd(&deg[d4.w], 1);
    *(uchar4*)&pos[e] = p4;
  } else {
    for (; e < E; ++e) pos[e] = (unsigned char)atomicAdd(&deg[dst[e]], 1);
  }
}

// fused: per-block degree sums + inv_s = rsqrt(deg+1) + gmsum zeroing
__global__ void scan_partial_kernel(const int* __restrict__ deg, float* __restrict__ inv_s,
                                    int* __restrict__ bsum, float* __restrict__ gmsum, int GH,
                                    int N) {
  __shared__ int s[256];
  int i = blockIdx.x * 256 + threadIdx.x;
  if (i < GH) gmsum[i] = 0.f;
  int d = (i < N) ? deg[i] : 0;
  if (i < N) inv_s[i] = rsqrtf((float)(d + 1));  // +1 self loop
  s[threadIdx.x] = d;
  __syncthreads();
  for (int off = 128; off > 0; off >>= 1) {
    if (threadIdx.x < off) s[threadIdx.x] += s[threadIdx.x + off];
    __syncthreads();
  }
  if (threadIdx.x == 0) bsum[blockIdx.x] = s[0];
}

// merged block-offset + final scan
__global__ void scan_final_kernel(const int* __restrict__ deg, const int* __restrict__ bsum,
                                  int* __restrict__ row_off, int NB, int N) {
  __shared__ int s[256];
  __shared__ int s2[256];
  int tid = threadIdx.x;
  int v2 = (tid < blockIdx.x && tid < NB) ? bsum[tid] : 0;
  s2[tid] = v2;
  __syncthreads();
  for (int off = 128; off > 0; off >>= 1) {
    if (tid < off) s2[tid] += s2[tid + off];
    __syncthreads();
  }
  int boff = s2[0];
  __syncthreads();
  int i = blockIdx.x * 256 + tid;
  int v = (i < N) ? deg[i] : 0;
  s[tid] = v;
  __syncthreads();
  for (int off = 1; off < 256; off <<= 1) {
    int t = (tid >= off) ? s[tid - off] : 0;
    __syncthreads();
    s[tid] += t;
    __syncthreads();
  }
  if (i < N) row_off[i] = boff + s[tid] - v;
  if (blockIdx.x == NB - 1 && tid == 255) row_off[N] = boff + s[255];
}

// merged: (a) no-atomic CSR scatter, (b) u_x fp8 prep (2-slice slice-major),
// (c) fp8 weight transposes.
__global__ void fill_prep_kernel(const int* __restrict__ src, const int* __restrict__ dst,
                                 const unsigned char* __restrict__ pos,
                                 const int* __restrict__ row_off, int* __restrict__ col, int E,
                                 int FB, const float* __restrict__ x,
                                 const float* __restrict__ inv_s, unsigned* __restrict__ u,
                                 int total_dw, const float* __restrict__ W0,
                                 const float* __restrict__ Ws, unsigned char* __restrict__ Wt0,
                                 unsigned char* __restrict__ WtS) {
  const int FH = 128 * 256, HH = 256 * 256;
  int b = blockIdx.x;
  if (b < FB) {  // CSR scatter: 4 edges/thread
    int t = b * 256 + threadIdx.x;
    int e = t * 4;
    if (e + 3 < E) {
      int4 s4 = *(const int4*)&src[e];
      int4 d4 = *(const int4*)&dst[e];
      uchar4 p4 = *(const uchar4*)&pos[e];
      col[row_off[d4.x] + p4.x] = s4.x;
      col[row_off[d4.y] + p4.y] = s4.y;
      col[row_off[d4.z] + p4.z] = s4.z;
      col[row_off[d4.w] + p4.w] = s4.w;
    } else {
      for (; e < E; ++e) col[row_off[dst[e]] + pos[e]] = src[e];
    }
  } else {
    int idx = (b - FB) * 256 + threadIdx.x;
    if (idx < total_dw) {  // u_x fp8, slice-major [2][N][64B]
      int i = idx >> 5;       // node (32 dwords per 128-ch row)
      int q = idx & 31;       // dword within row
      int slice = q >> 4;     // 0: ch 0..63, 1: ch 64..127
      int qq = q & 15;        // dword within 64B slice
      float s = inv_s[i];
      float4 v = *(const float4*)&x[(size_t)idx * 4];
      int Nn = total_dw >> 5;
      u[(size_t)slice * Nn * 16 + (size_t)i * 16 + qq] =
          pack4_fp8(s * v.x, s * v.y, s * v.z, s * v.w);
    } else {
      int w = idx - total_dw;
      if (w < FH) {
        int k = w >> 8, n = w & 255;
        Wt0[n * 128 + k] = f2fp8(W0[w]);
      } else {
        int t2 = w - FH;
        if (t2 < 3 * HH) {
          int l = t2 >> 16;
          int rem = t2 & 65535;
          int k = rem >> 8, n = rem & 255;
          WtS[l * HH + n * 256 + k] = f2fp8(Ws[t2]);
        }
      }
    }
  }
}

// ----------------------------- aggregate (fp8 gather) ------------------------
// No-shuffle geometry; slice-major u; aggA output row-major.
// Layer 0: u_x [2][N][64B]; slice=blockIdx&1 (3.2MB region fits per-XCD L2,
// 4 XCDs per slice). 4-lane group owns one node's 64B slice.
__global__ __launch_bounds__(256) void aggregate_fp8_sm2_kernel(
    const unsigned char* __restrict__ u, const int* __restrict__ row_off,
    const int* __restrict__ col, const float* __restrict__ inv_s,
    unsigned char* __restrict__ out, int N) {
  int slice = blockIdx.x & 1;
  int nb = blockIdx.x >> 1;
  int lane = threadIdx.x & 63;
  int wave = threadIdx.x >> 6;
  int grp = lane >> 2;  // 16 node-groups per wave
  int c = lane & 3;     // 4 lanes x 16B = 64B slice
  int i = nb * 64 + wave * 16 + grp;
  if (i >= N) return;
  int e0 = row_off[i], e1 = row_off[i + 1];
  int last = e1 - 1;
  const unsigned char* base = u + (size_t)slice * N * 64;
  unsigned cofs = c * 16;
  float acc[16] = {};
  for (int e = e0; e < e1; e += 4) {
    unsigned off[4];
    unsigned msk[4];
#pragma unroll
    for (int q = 0; q < 4; ++q) {
      int ee = e + q;
      bool v = ee < e1;
      int j = col[v ? ee : last];
      off[q] = (unsigned)j * 64 + cofs;
      msk[q] = v ? 0xffffffffu : 0u;
    }
    uint4 r[4];
#pragma unroll
    for (int q = 0; q < 4; ++q) r[q] = *(const uint4*)(base + off[q]);
#pragma unroll
    for (int q = 0; q < 4; ++q) acc16_fp8(acc, r[q], msk[q]);
  }
  uint4 self = *(const uint4*)(base + (size_t)i * 64 + cofs);
  acc16_fp8(acc, self, 0xffffffffu);
  float s = inv_s[i];
  uint4 o;
  o.x = pack4_fp8(s * acc[0], s * acc[1], s * acc[2], s * acc[3]);
  o.y = pack4_fp8(s * acc[4], s * acc[5], s * acc[6], s * acc[7]);
  o.z = pack4_fp8(s * acc[8], s * acc[9], s * acc[10], s * acc[11]);
  o.w = pack4_fp8(s * acc[12], s * acc[13], s * acc[14], s * acc[15]);
  // aggA row-major [N][128]
  *(uint4*)(out + (size_t)i * 128 + slice * 64 + cofs) = o;
}

// CH=256 layers: uA [4][N][64B]; slice=blockIdx&3 (3.2MB region fits per-XCD
// L2, 2 XCDs per slice -> compulsory fetch ~26MB vs r16's 61MB).
__global__ __launch_bounds__(256) void aggregate_fp8_sm4_kernel(
    const unsigned char* __restrict__ u, const int* __restrict__ row_off,
    const int* __restrict__ col, const float* __restrict__ inv_s,
    unsigned char* __restrict__ out, int N) {
  int slice = blockIdx.x & 3;
  int nb = blockIdx.x >> 2;
  int lane = threadIdx.x & 63;
  int wave = threadIdx.x >> 6;
  int grp = lane >> 2;  // 16 node-groups per wave
  int c = lane & 3;     // 4 lanes x 16B = 64B slice
  int i = nb * 64 + wave * 16 + grp;
  if (i >= N) return;
  int e0 = row_off[i], e1 = row_off[i + 1];
  int last = e1 - 1;
  const unsigned char* base = u + (size_t)slice * N * 64;
  unsigned cofs = c * 16;
  float acc[16] = {};
  for (int e = e0; e < e1; e += 4) {
    unsigned off[4];
    unsigned msk[4];
#pragma unroll
    for (int q = 0; q < 4; ++q) {
      int ee = e + q;
      bool v = ee < e1;
      int j = col[v ? ee : last];
      off[q] = (unsigned)j * 64 + cofs;
      msk[q] = v ? 0xffffffffu : 0u;
    }
    uint4 r[4];
#pragma unroll
    for (int q = 0; q < 4; ++q) r[q] = *(const uint4*)(base + off[q]);
#pragma unroll
    for (int q = 0; q < 4; ++q) acc16_fp8(acc, r[q], msk[q]);
  }
  uint4 self = *(const uint4*)(base + (size_t)i * 64 + cofs);
  acc16_fp8(acc, self, 0xffffffffu);
  float s = inv_s[i];
  uint4 o;
  o.x = pack4_fp8(s * acc[0], s * acc[1], s * acc[2], s * acc[3]);
  o.y = pack4_fp8(s * acc[4], s * acc[5], s * acc[6], s * acc[7]);
  o.z = pack4_fp8(s * acc[8], s * acc[9], s * acc[10], s * acc[11]);
  o.w = pack4_fp8(s * acc[12], s * acc[13], s * acc[14], s * acc[15]);
  // aggA row-major [N][256]
  *(uint4*)(out + (size_t)i * 256 + slice * 64 + cofs) = o;
}

// ----------------------------- fp8 MFMA GEMM ---------------------------------
// C[M,256] = A[M,K] @ W[K,256] (+bias, opt relu), A/B fp8 e4m3.
// BM=128, 8 waves, 512 threads, BK=128 (LDS 55KB).
// OUTMODE 1: uA slice-major [4][M][64B]: u4[cc>>6][gr][cc&63]
// OUTMODE 2: atomicAdd into gmsum[batch[r]*256+cc] (fused mean-pool)
template <int K, bool RELU, int OUTMODE>
__global__ __launch_bounds__(512) void gemm_kernel(
    const unsigned char* __restrict__ A,   // [M][K] fp8 (row-major)
    const unsigned char* __restrict__ Bt,  // [256][K] fp8 (W transposed)
    const float* __restrict__ bias,        // [256]
    const float* __restrict__ inv_s, const int* __restrict__ batch,
    const float* __restrict__ gh,          // [G][256]
    void* __restrict__ outp,               // fp8 u (slice-major) or float gmsum
    int M) {
  constexpr int BK = 128;   // fp8 elems per stage
  constexpr int LDT = 144;  // bytes per row: 128 data + 16 pad (16B-aligned)
  __shared__ unsigned char As[128 * LDT];
  __shared__ unsigned char Bs[256 * LDT];
  int tid = threadIdx.x;
  int wave = tid >> 6, lane = tid & 63;
  int quad = lane >> 4, l15 = lane & 15;
  int wr = wave >> 2, wc = wave & 3;
  int row0 = blockIdx.x * 128;
  f32x4 acc[4][4];
#pragma unroll
  for (int m = 0; m < 4; ++m)
#pragma unroll
    for (int n = 0; n < 4; ++n) acc[m][n] = (f32x4){0.f, 0.f, 0.f, 0.f};

  for (int k0 = 0; k0 < K; k0 += BK) {
#pragma unroll
    for (int p = 0; p < 2; ++p) {  // stage A: 128 rows x 128 fp8
      int uidx = tid + p * 512;
      int r = uidx >> 3, kq = uidx & 7;
      int gr = row0 + r;
      uint4 v = make_uint4(0u, 0u, 0u, 0u);
      if (gr < M) v = *(const uint4*)&A[(size_t)gr * K + k0 + kq * 16];
      *(uint4*)&As[r * LDT + kq * 16] = v;
    }
#pragma unroll
    for (int p = 0; p < 4; ++p) {  // stage B: 256 rows x 128 fp8
      int uidx = tid + p * 512;
      int n = uidx >> 3, kq = uidx & 7;
      *(uint4*)&Bs[n * LDT + kq * 16] = *(const uint4*)&Bt[(size_t)n * K + k0 + kq * 16];
    }
    __syncthreads();
#pragma unroll
    for (int s = 0; s < 4; ++s) {  // four K=32 sub-steps per stage
      long long af[4], bfr[4];
#pragma unroll
      for (int m = 0; m < 4; ++m)
        af[m] = *(const long long*)&As[(wr * 64 + m * 16 + l15) * LDT + s * 32 + quad * 8];
#pragma unroll
      for (int n = 0; n < 4; ++n)
        bfr[n] = *(const long long*)&Bs[(wc * 64 + n * 16 + l15) * LDT + s * 32 + quad * 8];
#pragma unroll
      for (int m = 0; m < 4; ++m)
#pragma unroll
        for (int n = 0; n < 4; ++n)
          acc[m][n] =
              __builtin_amdgcn_mfma_f32_16x16x32_fp8_fp8(af[m], bfr[n], acc[m][n], 0, 0, 0);
    }
    if (k0 + BK < K) __syncthreads();
  }
  // epilogue: C/D map col=lane&15, row=(lane>>4)*4+reg
  if (OUTMODE == 1) {
    unsigned char* u4 = (unsigned char*)outp;
#pragma unroll
    for (int m = 0; m < 4; ++m) {
#pragma unroll
      for (int r = 0; r < 4; ++r) {
        int gr = row0 + wr * 64 + m * 16 + quad * 4 + r;
        if (gr >= M) continue;
        float sv = inv_s[gr];
        int bofs = batch[gr] * 256;
#pragma unroll
        for (int n = 0; n < 4; ++n) {
          int cc = wc * 64 + n * 16 + l15;
          float v = acc[m][n][r] + bias[cc];
          if (RELU) v = fmaxf(v, 0.f);
          v = sv * (v + gh[bofs + cc]);
          // slice-major: [cc>>6][gr][cc&63]
          u4[(size_t)(cc >> 6) * M * 64 + (size_t)gr * 64 + (cc & 63)] = f2fp8(v);
        }
      }
    }
  } else {
    // fused mean-pool: batch sorted -> run-compress, flush 4 atomics per run.
    float* gmsum = (float*)outp;
    float psum[4] = {0.f, 0.f, 0.f, 0.f};
    int cur_b = -1;
#pragma unroll
    for (int m = 0; m < 4; ++m) {
#pragma unroll
      for (int r = 0; r < 4; ++r) {
        int gr = row0 + wr * 64 + m * 16 + quad * 4 + r;
        if (gr >= M) continue;
        int b = batch[gr] * 256;
        if (b != cur_b) {
          if (cur_b >= 0) {
#pragma unroll
            for (int n = 0; n < 4; ++n)
              atomicAdd(&gmsum[cur_b + wc * 64 + n * 16 + l15], psum[n]);
          }
          cur_b = b;
#pragma unroll
          for (int n = 0; n < 4; ++n) psum[n] = 0.f;
        }
#pragma unroll
        for (int n = 0; n < 4; ++n) {
          int cc = wc * 64 + n * 16 + l15;
          float v = acc[m][n][r] + bias[cc];
          if (RELU) v = fmaxf(v, 0.f);
          psum[n] += v;
        }
      }
    }
    if (cur_b >= 0) {
#pragma unroll
      for (int n = 0; n < 4; ++n)
        atomicAdd(&gmsum[cur_b + wc * 64 + n * 16 + l15], psum[n]);
    }
  }
}

// ----------------------------- final ----------------------------------------

__global__ void final_kernel(const float* __restrict__ gmsum, const int* __restrict__ batch,
                             int N, const float* __restrict__ gh,
                             const float* __restrict__ Wlin, const float* __restrict__ blin,
                             float* __restrict__ y, float* __restrict__ gm_out, int G) {
  int g = blockIdx.x;
  int c = threadIdx.x;
  __shared__ float row[256];
  __shared__ int cnt_s;
  if (c == 0) cnt_s = lbound(batch, N, g + 1) - lbound(batch, N, g);
  __syncthreads();
  float v = gmsum[g * 256 + c] / fmaxf((float)cnt_s, 1.0f) + gh[g * 256 + c];
  gm_out[g * 256 + c] = v;
  row[c] = v;
  __syncthreads();
  if (c < 10) {
    float acc = blin[c];
    for (int k = 0; k < 256; ++k) acc += row[k] * Wlin[k * 10 + c];
    y[g * 10 + c] = acc;
  }
}

// ----------------------------- launch ----------------------------------------

extern "C" void kernel_launch(void* const* d_in, const int* in_sizes, int n_in,
                              void* d_out, int out_size, void* d_ws, size_t ws_size,
                              hipStream_t stream) {
  const float* x = (const float*)d_in[0];
  const int* ei = (const int*)d_in[1];
  const int* batch = (const int*)d_in[2];
  const float* gh = (const float*)d_in[3];
  const float* W0 = (const float*)d_in[4];
  const float* b0 = (const float*)d_in[5];
  const float* Ws = (const float*)d_in[6];
  const float* bs = (const float*)d_in[7];
  const float* Wlin = (const float*)d_in[8];
  const float* blin = (const float*)d_in[9];
  float* out = (float*)d_out;

  const int N = in_sizes[2];
  const int E = in_sizes[1] / 2;
  const int G = in_sizes[3] / 256;
  const int H = 256, L = 3, C = 10, F = 128;

  char* ws = (char*)d_ws;
  size_t off = 0;
  auto alloc = [&](size_t bytes) {
    void* p = ws + off;
    off += (bytes + 255) & ~(size_t)255;
    return p;
  };
  int* deg = (int*)alloc((size_t)N * 4);
  float* gmsum = (float*)alloc((size_t)G * H * 4);
  int* row_off = (int*)alloc((size_t)(N + 1) * 4);
  int* bsum = (int*)alloc(256 * 4);
  int* col = (int*)alloc((size_t)E * 4);
  unsigned char* pos = (unsigned char*)alloc((size_t)E);
  float* inv_s = (float*)alloc((size_t)N * 4);
  unsigned char* u_x = (unsigned char*)alloc((size_t)N * F);    // fp8 s*x, [2][N][64]
  unsigned char* uA = (unsigned char*)alloc((size_t)N * H);     // fp8 s*(h+res), [4][N][64]
  unsigned char* aggA = (unsigned char*)alloc((size_t)N * H);   // fp8 agg out, row-major
  unsigned char* Wt0 = (unsigned char*)alloc((size_t)F * H);    // fp8 [256][128]
  unsigned char* WtS = (unsigned char*)alloc((size_t)L * H * H);

  const int* srcv = ei;
  const int* dstv = ei + E;

  hipMemsetAsync(deg, 0, (size_t)N * 4, stream);

  int NB = (N + 255) / 256;
  int CPB = ((E + 3) / 4 + 255) / 256;
  count_pos_kernel<<<CPB, 256, 0, stream>>>(dstv, deg, pos, E);
  scan_partial_kernel<<<NB, 256, 0, stream>>>(deg, inv_s, bsum, gmsum, G * H, N);
  scan_final_kernel<<<NB, 256, 0, stream>>>(deg, bsum, row_off, NB, N);

  int FB = ((E + 3) / 4 + 255) / 256;
  int UXDW = N * (F / 4);
  int TW = F * H + 3 * H * H;
  int PREPB = (UXDW + TW + 255) / 256;
  fill_prep_kernel<<<FB + PREPB, 256, 0, stream>>>(srcv, dstv, pos, row_off, col, E, FB, x,
                                                   inv_s, (unsigned*)u_x, UXDW, W0, Ws, Wt0,
                                                   WtS);

  int AGG2_GRID = ((N + 63) / 64) * 2;  // node-blocks x 2 slices
  int AGG4_GRID = ((N + 63) / 64) * 4;  // node-blocks x 4 slices
  int GEMM_GRID = (N + 127) / 128;

  // layer 0: sm2 agg(u_x) -> fp8 GEMM K=128 (no relu) -> uA (slice-major)
  aggregate_fp8_sm2_kernel<<<AGG2_GRID, 256, 0, stream>>>(u_x, row_off, col, inv_s, aggA, N);
  gemm_kernel<128, false, 1><<<GEMM_GRID, 512, 0, stream>>>(aggA, Wt0, b0, inv_s, batch, gh,
                                                            uA, N);
  // layers 1..2: sm4 agg(uA) -> fp8 GEMM relu -> uA (slice-major)
  for (int l = 0; l < 2; ++l) {
    aggregate_fp8_sm4_kernel<<<AGG4_GRID, 256, 0, stream>>>(uA, row_off, col, inv_s, aggA, N);
    gemm_kernel<256, true, 1><<<GEMM_GRID, 512, 0, stream>>>(
        aggA, WtS + (size_t)l * H * H, bs + (size_t)l * H, inv_s, batch, gh, uA, N);
  }
  // layer 3: sm4 agg -> fp8 GEMM relu + fused mean-pool
  aggregate_fp8_sm4_kernel<<<AGG4_GRID, 256, 0, stream>>>(uA, row_off, col, inv_s, aggA, N);
  gemm_kernel<256, true, 2><<<GEMM_GRID, 512, 0, stream>>>(
      aggA, WtS + (size_t)2 * H * H, bs + (size_t)2 * H, inv_s, batch, gh, gmsum, N);

  final_kernel<<<G, 256, 0, stream>>>(gmsum, batch, N, gh, Wlin, blin, out,
                                      out + (size_t)G * C, G);
}

// Round 18
// 345.441 us; speedup vs baseline: 1.0540x; 1.0540x over previous
//
#include <hip/hip_runtime.h>

// ---------------------------------------------------------------------------
// BlockGNN on MI355X, round 20 (= r18 revert; r19's slice-major 4-slice
// layout regressed +16.5us: per-edge overhead duplication (2x->4x) exceeded
// the L2-capacity win. Slicing axis now fully explored: 1 slice (r12, more
// fetch), 2 slices interleaved (r16/r18, optimum), 4 slices slice-major
// (r19, overhead-bound). This is the verified 347.6us composition.)
//   - GEMM: fp8 e4m3 end-to-end, BK=128 stages (LDS 55KB), BM=128/512thr.
//   - aggs: no-shuffle fp8 gathers; CH=256 XCD-2-sliced; CH=128 unsliced.
//   - CSR: fused count+pos (u8), 2-kernel scan, merged fill+prep.
//   - fused mean-pool GEMM epilogue, bsearch final.
// ---------------------------------------------------------------------------

typedef float f32x4 __attribute__((ext_vector_type(4)));
typedef float f32x2 __attribute__((ext_vector_type(2)));

__device__ inline float bf2f(unsigned short u) {
  union { unsigned int i; float f; } v;
  v.i = (unsigned int)u << 16;
  return v.f;
}
__device__ inline unsigned short f2bf(float f) {
  union { unsigned int i; float f; } v;
  v.f = f;
  unsigned int i = v.i;
  return (unsigned short)((i + 0x7fffu + ((i >> 16) & 1u)) >> 16);  // RNE
}
// fp8 e4m3 pack of 4 floats -> dword (bytes 0..3)
__device__ inline unsigned pack4_fp8(float a, float b, float c, float d) {
  int r = 0;
  r = __builtin_amdgcn_cvt_pk_fp8_f32(a, b, r, false);
  r = __builtin_amdgcn_cvt_pk_fp8_f32(c, d, r, true);
  return (unsigned)r;
}
__device__ inline unsigned char f2fp8(float v) {
  return (unsigned char)((unsigned)__builtin_amdgcn_cvt_pk_fp8_f32(v, v, 0, false) & 0xffu);
}
// accumulate 16 fp8 channels (one uint4) into acc[16]; msk==0 squashes (+0.0)
__device__ inline void acc16_fp8(float* acc, uint4 r, unsigned msk) {
  unsigned w[4] = {r.x, r.y, r.z, r.w};
#pragma unroll
  for (int d = 0; d < 4; ++d) {
    int v = (int)(w[d] & msk);
    f32x2 lo = __builtin_amdgcn_cvt_pk_f32_fp8(v, false);
    f32x2 hi = __builtin_amdgcn_cvt_pk_f32_fp8(v, true);
    acc[4 * d + 0] += lo[0];
    acc[4 * d + 1] += lo[1];
    acc[4 * d + 2] += hi[0];
    acc[4 * d + 3] += hi[1];
  }
}
__device__ inline int lbound(const int* a, int n, int key) {
  int lo = 0, hi = n;
  while (lo < hi) {
    int mid = (lo + hi) >> 1;
    if (a[mid] < key) lo = mid + 1; else hi = mid;
  }
  return lo;
}

// ----------------------------- CSR build -----------------------------------

// counting pass that also records each edge's slot (atomicAdd return value).
// 4 edges/thread: int4 dst read, uchar4 pos write (max deg ~45 << 255).
__global__ void count_pos_kernel(const int* __restrict__ dst, int* __restrict__ deg,
                                 unsigned char* __restrict__ pos, int E) {
  int t = blockIdx.x * blockDim.x + threadIdx.x;
  int e = t * 4;
  if (e + 3 < E) {
    int4 d4 = *(const int4*)&dst[e];
    uchar4 p4;
    p4.x = (unsigned char)atomicAdd(&deg[d4.x], 1);
    p4.y = (unsigned char)atomicAdd(&deg[d4.y], 1);
    p4.z = (unsigned char)atomicAdd(&deg[d4.z], 1);
    p4.w = (unsigned char)atomicAdd(&deg[d4.w], 1);
    *(uchar4*)&pos[e] = p4;
  } else {
    for (; e < E; ++e) pos[e] = (unsigned char)atomicAdd(&deg[dst[e]], 1);
  }
}

// fused: per-block degree sums + inv_s = rsqrt(deg+1) + gmsum zeroing
__global__ void scan_partial_kernel(const int* __restrict__ deg, float* __restrict__ inv_s,
                                    int* __restrict__ bsum, float* __restrict__ gmsum, int GH,
                                    int N) {
  __shared__ int s[256];
  int i = blockIdx.x * 256 + threadIdx.x;
  if (i < GH) gmsum[i] = 0.f;
  int d = (i < N) ? deg[i] : 0;
  if (i < N) inv_s[i] = rsqrtf((float)(d + 1));  // +1 self loop
  s[threadIdx.x] = d;
  __syncthreads();
  for (int off = 128; off > 0; off >>= 1) {
    if (threadIdx.x < off) s[threadIdx.x] += s[threadIdx.x + off];
    __syncthreads();
  }
  if (threadIdx.x == 0) bsum[blockIdx.x] = s[0];
}

// merged block-offset + final scan: each block reduces bsum[0..blockIdx) for
// its own offset (<=256 values), then does its local scan. Last block also
// writes row_off[N].
__global__ void scan_final_kernel(const int* __restrict__ deg, const int* __restrict__ bsum,
                                  int* __restrict__ row_off, int NB, int N) {
  __shared__ int s[256];
  __shared__ int s2[256];
  int tid = threadIdx.x;
  int v2 = (tid < blockIdx.x && tid < NB) ? bsum[tid] : 0;
  s2[tid] = v2;
  __syncthreads();
  for (int off = 128; off > 0; off >>= 1) {
    if (tid < off) s2[tid] += s2[tid + off];
    __syncthreads();
  }
  int boff = s2[0];
  __syncthreads();
  int i = blockIdx.x * 256 + tid;
  int v = (i < N) ? deg[i] : 0;
  s[tid] = v;
  __syncthreads();
  for (int off = 1; off < 256; off <<= 1) {
    int t = (tid >= off) ? s[tid - off] : 0;
    __syncthreads();
    s[tid] += t;
    __syncthreads();
  }
  if (i < N) row_off[i] = boff + s[tid] - v;
  if (blockIdx.x == NB - 1 && tid == 255) row_off[N] = boff + s[255];
}

// merged: (a) no-atomic CSR scatter, (b) u_x fp8 prep, (c) fp8 weight transposes.
__global__ void fill_prep_kernel(const int* __restrict__ src, const int* __restrict__ dst,
                                 const unsigned char* __restrict__ pos,
                                 const int* __restrict__ row_off, int* __restrict__ col, int E,
                                 int FB, const float* __restrict__ x,
                                 const float* __restrict__ inv_s, unsigned* __restrict__ u,
                                 int total_dw, const float* __restrict__ W0,
                                 const float* __restrict__ Ws, unsigned char* __restrict__ Wt0,
                                 unsigned char* __restrict__ WtS) {
  const int FH = 128 * 256, HH = 256 * 256;
  int b = blockIdx.x;
  if (b < FB) {  // CSR scatter: 4 edges/thread
    int t = b * 256 + threadIdx.x;
    int e = t * 4;
    if (e + 3 < E) {
      int4 s4 = *(const int4*)&src[e];
      int4 d4 = *(const int4*)&dst[e];
      uchar4 p4 = *(const uchar4*)&pos[e];
      col[row_off[d4.x] + p4.x] = s4.x;
      col[row_off[d4.y] + p4.y] = s4.y;
      col[row_off[d4.z] + p4.z] = s4.z;
      col[row_off[d4.w] + p4.w] = s4.w;
    } else {
      for (; e < E; ++e) col[row_off[dst[e]] + pos[e]] = src[e];
    }
  } else {
    int idx = (b - FB) * 256 + threadIdx.x;
    if (idx < total_dw) {  // u_x fp8 (32 dwords per 128-ch row)
      int i = idx >> 5;
      float s = inv_s[i];
      float4 v = *(const float4*)&x[(size_t)idx * 4];
      u[idx] = pack4_fp8(s * v.x, s * v.y, s * v.z, s * v.w);
    } else {
      int w = idx - total_dw;
      if (w < FH) {
        int k = w >> 8, n = w & 255;
        Wt0[n * 128 + k] = f2fp8(W0[w]);
      } else {
        int t2 = w - FH;
        if (t2 < 3 * HH) {
          int l = t2 >> 16;
          int rem = t2 & 65535;
          int k = rem >> 8, n = rem & 255;
          WtS[l * HH + n * 256 + k] = f2fp8(Ws[t2]);
        }
      }
    }
  }
}

// ----------------------------- aggregate (fp8 gather) ------------------------
// No-shuffle geometry (r16/r17): an 8-lane group owns one node's 128B line;
// lane-private 16-channel accumulation over all edges (4-deep clamped batch,
// AND-mask squash); zero cross-lane ops.
// Layer 0 (CH=128): the 128B line IS the whole row; no slicing.
__global__ __launch_bounds__(256) void aggregate_fp8_ns128_kernel(
    const unsigned char* __restrict__ u, const int* __restrict__ row_off,
    const int* __restrict__ col, const float* __restrict__ inv_s,
    unsigned char* __restrict__ out, int N) {
  constexpr int CH = 128;
  int lane = threadIdx.x & 63;
  int wave = threadIdx.x >> 6;
  int grp = lane >> 3;  // 8 node-groups per wave
  int c = lane & 7;     // 8 lanes x 16B = 128B row
  int i = blockIdx.x * 32 + wave * 8 + grp;
  if (i >= N) return;
  int e0 = row_off[i], e1 = row_off[i + 1];
  int last = e1 - 1;
  unsigned cofs = c * 16;
  float acc[16] = {};
  for (int e = e0; e < e1; e += 4) {
    unsigned off[4];
    unsigned msk[4];
#pragma unroll
    for (int q = 0; q < 4; ++q) {
      int ee = e + q;
      bool v = ee < e1;
      int j = col[v ? ee : last];
      off[q] = (unsigned)j * CH + cofs;
      msk[q] = v ? 0xffffffffu : 0u;
    }
    uint4 r[4];
#pragma unroll
    for (int q = 0; q < 4; ++q) r[q] = *(const uint4*)(u + off[q]);
#pragma unroll
    for (int q = 0; q < 4; ++q) acc16_fp8(acc, r[q], msk[q]);
  }
  uint4 self = *(const uint4*)(u + (size_t)i * CH + cofs);
  acc16_fp8(acc, self, 0xffffffffu);
  float s = inv_s[i];
  uint4 o;
  o.x = pack4_fp8(s * acc[0], s * acc[1], s * acc[2], s * acc[3]);
  o.y = pack4_fp8(s * acc[4], s * acc[5], s * acc[6], s * acc[7]);
  o.z = pack4_fp8(s * acc[8], s * acc[9], s * acc[10], s * acc[11]);
  o.w = pack4_fp8(s * acc[12], s * acc[13], s * acc[14], s * acc[15]);
  *(uint4*)(out + (size_t)i * CH + cofs) = o;
}

// CH=256 layers: XCD-sliced (slice=blockIdx&1 -> parity affinity; each slice
// = 128 fp8 ch = one 128B line; per-XCD L2 holds only its 6.4MB half).
__global__ __launch_bounds__(256) void aggregate_fp8_ns_kernel(
    const unsigned char* __restrict__ u, const int* __restrict__ row_off,
    const int* __restrict__ col, const float* __restrict__ inv_s,
    unsigned char* __restrict__ out, int N) {
  constexpr int CH = 256;
  int slice = blockIdx.x & 1;
  int nb = blockIdx.x >> 1;
  int lane = threadIdx.x & 63;
  int wave = threadIdx.x >> 6;
  int grp = lane >> 3;  // 8 node-groups per wave
  int c = lane & 7;     // 8 lanes x 16B = 128B slice
  int i = nb * 32 + wave * 8 + grp;
  if (i >= N) return;
  int e0 = row_off[i], e1 = row_off[i + 1];
  int last = e1 - 1;
  unsigned sofs = (unsigned)slice * 128 + c * 16;
  float acc[16] = {};
  for (int e = e0; e < e1; e += 4) {
    unsigned off[4];
    unsigned msk[4];
#pragma unroll
    for (int q = 0; q < 4; ++q) {
      int ee = e + q;
      bool v = ee < e1;
      int j = col[v ? ee : last];
      off[q] = (unsigned)j * CH + sofs;
      msk[q] = v ? 0xffffffffu : 0u;
    }
    uint4 r[4];
#pragma unroll
    for (int q = 0; q < 4; ++q) r[q] = *(const uint4*)(u + off[q]);
#pragma unroll
    for (int q = 0; q < 4; ++q) acc16_fp8(acc, r[q], msk[q]);
  }
  uint4 self = *(const uint4*)(u + (size_t)i * CH + sofs);
  acc16_fp8(acc, self, 0xffffffffu);
  float s = inv_s[i];
  uint4 o;
  o.x = pack4_fp8(s * acc[0], s * acc[1], s * acc[2], s * acc[3]);
  o.y = pack4_fp8(s * acc[4], s * acc[5], s * acc[6], s * acc[7]);
  o.z = pack4_fp8(s * acc[8], s * acc[9], s * acc[10], s * acc[11]);
  o.w = pack4_fp8(s * acc[12], s * acc[13], s * acc[14], s * acc[15]);
  *(uint4*)(out + (size_t)i * CH + sofs) = o;
}

// ----------------------------- fp8 MFMA GEMM ---------------------------------
// C[M,256] = A[M,K] @ W[K,256] (+bias, opt relu), A/B fp8 e4m3.
// BM=128, 8 waves (2 row-halves x 4 col-quarters), 512 threads, BK=128
// (LDS 55KB, 2 blocks/CU; grid 391 on 256 CUs so cap is immaterial).
// K=256: 2 stages/4 barriers; K=128: one stage.
// OUTMODE 1: out = fp8( inv_s[r] * (C + gh[batch[r]]) )   (next layer's u)
// OUTMODE 2: atomicAdd into gmsum[batch[r]*256+cc]        (fused mean-pool)
template <int K, bool RELU, int OUTMODE>
__global__ __launch_bounds__(512) void gemm_kernel(
    const unsigned char* __restrict__ A,   // [M][K] fp8
    const unsigned char* __restrict__ Bt,  // [256][K] fp8 (W transposed)
    const float* __restrict__ bias,        // [256]
    const float* __restrict__ inv_s, const int* __restrict__ batch,
    const float* __restrict__ gh,          // [G][256]
    void* __restrict__ outp,               // fp8 u [M][256] or float gmsum
    int M) {
  constexpr int BK = 128;   // fp8 elems per stage
  constexpr int LDT = 144;  // bytes per row: 128 data + 16 pad (16B-aligned)
  __shared__ unsigned char As[128 * LDT];
  __shared__ unsigned char Bs[256 * LDT];
  int tid = threadIdx.x;
  int wave = tid >> 6, lane = tid & 63;
  int quad = lane >> 4, l15 = lane & 15;
  int wr = wave >> 2, wc = wave & 3;
  int row0 = blockIdx.x * 128;
  f32x4 acc[4][4];
#pragma unroll
  for (int m = 0; m < 4; ++m)
#pragma unroll
    for (int n = 0; n < 4; ++n) acc[m][n] = (f32x4){0.f, 0.f, 0.f, 0.f};

  for (int k0 = 0; k0 < K; k0 += BK) {
    // stage A: 128 rows x 128 fp8 = 1024 uint4; 2 per thread
#pragma unroll
    for (int p = 0; p < 2; ++p) {
      int uidx = tid + p * 512;
      int r = uidx >> 3, kq = uidx & 7;
      int gr = row0 + r;
      uint4 v = make_uint4(0u, 0u, 0u, 0u);
      if (gr < M) v = *(const uint4*)&A[(size_t)gr * K + k0 + kq * 16];
      *(uint4*)&As[r * LDT + kq * 16] = v;
    }
    // stage B: 256 rows x 128 fp8 = 2048 uint4; 4 per thread
#pragma unroll
    for (int p = 0; p < 4; ++p) {
      int uidx = tid + p * 512;
      int n = uidx >> 3, kq = uidx & 7;
      *(uint4*)&Bs[n * LDT + kq * 16] = *(const uint4*)&Bt[(size_t)n * K + k0 + kq * 16];
    }
    __syncthreads();
#pragma unroll
    for (int s = 0; s < 4; ++s) {  // four K=32 sub-steps per stage
      long long af[4], bfr[4];
#pragma unroll
      for (int m = 0; m < 4; ++m)
        af[m] = *(const long long*)&As[(wr * 64 + m * 16 + l15) * LDT + s * 32 + quad * 8];
#pragma unroll
      for (int n = 0; n < 4; ++n)
        bfr[n] = *(const long long*)&Bs[(wc * 64 + n * 16 + l15) * LDT + s * 32 + quad * 8];
#pragma unroll
      for (int m = 0; m < 4; ++m)
#pragma unroll
        for (int n = 0; n < 4; ++n)
          acc[m][n] =
              __builtin_amdgcn_mfma_f32_16x16x32_fp8_fp8(af[m], bfr[n], acc[m][n], 0, 0, 0);
    }
    if (k0 + BK < K) __syncthreads();
  }
  // epilogue: C/D map col=lane&15, row=(lane>>4)*4+reg
  if (OUTMODE == 1) {
#pragma unroll
    for (int m = 0; m < 4; ++m) {
#pragma unroll
      for (int r = 0; r < 4; ++r) {
        int gr = row0 + wr * 64 + m * 16 + quad * 4 + r;
        if (gr >= M) continue;
        float sv = inv_s[gr];
        int bofs = batch[gr] * 256;
#pragma unroll
        for (int n = 0; n < 4; ++n) {
          int cc = wc * 64 + n * 16 + l15;
          float v = acc[m][n][r] + bias[cc];
          if (RELU) v = fmaxf(v, 0.f);
          v = sv * (v + gh[bofs + cc]);
          ((unsigned char*)outp)[(size_t)gr * 256 + cc] = f2fp8(v);
        }
      }
    }
  } else {
    // fused mean-pool: batch sorted -> run-compress, flush 4 atomics per run.
    float* gmsum = (float*)outp;
    float psum[4] = {0.f, 0.f, 0.f, 0.f};
    int cur_b = -1;
#pragma unroll
    for (int m = 0; m < 4; ++m) {
#pragma unroll
      for (int r = 0; r < 4; ++r) {
        int gr = row0 + wr * 64 + m * 16 + quad * 4 + r;
        if (gr >= M) continue;
        int b = batch[gr] * 256;
        if (b != cur_b) {
          if (cur_b >= 0) {
#pragma unroll
            for (int n = 0; n < 4; ++n)
              atomicAdd(&gmsum[cur_b + wc * 64 + n * 16 + l15], psum[n]);
          }
          cur_b = b;
#pragma unroll
          for (int n = 0; n < 4; ++n) psum[n] = 0.f;
        }
#pragma unroll
        for (int n = 0; n < 4; ++n) {
          int cc = wc * 64 + n * 16 + l15;
          float v = acc[m][n][r] + bias[cc];
          if (RELU) v = fmaxf(v, 0.f);
          psum[n] += v;
        }
      }
    }
    if (cur_b >= 0) {
#pragma unroll
      for (int n = 0; n < 4; ++n)
        atomicAdd(&gmsum[cur_b + wc * 64 + n * 16 + l15], psum[n]);
    }
  }
}

// ----------------------------- final ----------------------------------------

__global__ void final_kernel(const float* __restrict__ gmsum, const int* __restrict__ batch,
                             int N, const float* __restrict__ gh,
                             const float* __restrict__ Wlin, const float* __restrict__ blin,
                             float* __restrict__ y, float* __restrict__ gm_out, int G) {
  int g = blockIdx.x;
  int c = threadIdx.x;
  __shared__ float row[256];
  __shared__ int cnt_s;
  if (c == 0) cnt_s = lbound(batch, N, g + 1) - lbound(batch, N, g);
  __syncthreads();
  float v = gmsum[g * 256 + c] / fmaxf((float)cnt_s, 1.0f) + gh[g * 256 + c];
  gm_out[g * 256 + c] = v;
  row[c] = v;
  __syncthreads();
  if (c < 10) {
    float acc = blin[c];
    for (int k = 0; k < 256; ++k) acc += row[k] * Wlin[k * 10 + c];
    y[g * 10 + c] = acc;
  }
}

// ----------------------------- launch ----------------------------------------

extern "C" void kernel_launch(void* const* d_in, const int* in_sizes, int n_in,
                              void* d_out, int out_size, void* d_ws, size_t ws_size,
                              hipStream_t stream) {
  const float* x = (const float*)d_in[0];
  const int* ei = (const int*)d_in[1];
  const int* batch = (const int*)d_in[2];
  const float* gh = (const float*)d_in[3];
  const float* W0 = (const float*)d_in[4];
  const float* b0 = (const float*)d_in[5];
  const float* Ws = (const float*)d_in[6];
  const float* bs = (const float*)d_in[7];
  const float* Wlin = (const float*)d_in[8];
  const float* blin = (const float*)d_in[9];
  float* out = (float*)d_out;

  const int N = in_sizes[2];
  const int E = in_sizes[1] / 2;
  const int G = in_sizes[3] / 256;
  const int H = 256, L = 3, C = 10, F = 128;

  char* ws = (char*)d_ws;
  size_t off = 0;
  auto alloc = [&](size_t bytes) {
    void* p = ws + off;
    off += (bytes + 255) & ~(size_t)255;
    return p;
  };
  int* deg = (int*)alloc((size_t)N * 4);
  float* gmsum = (float*)alloc((size_t)G * H * 4);
  int* row_off = (int*)alloc((size_t)(N + 1) * 4);
  int* bsum = (int*)alloc(256 * 4);
  int* col = (int*)alloc((size_t)E * 4);
  unsigned char* pos = (unsigned char*)alloc((size_t)E);
  float* inv_s = (float*)alloc((size_t)N * 4);
  unsigned char* u_x = (unsigned char*)alloc((size_t)N * F);    // fp8 s*x
  unsigned char* uA = (unsigned char*)alloc((size_t)N * H);     // fp8 s*(h+res)
  unsigned char* aggA = (unsigned char*)alloc((size_t)N * H);   // fp8 agg out / GEMM A
  unsigned char* Wt0 = (unsigned char*)alloc((size_t)F * H);    // fp8 [256][128]
  unsigned char* WtS = (unsigned char*)alloc((size_t)L * H * H);

  const int* srcv = ei;
  const int* dstv = ei + E;

  hipMemsetAsync(deg, 0, (size_t)N * 4, stream);

  int NB = (N + 255) / 256;
  int CPB = ((E + 3) / 4 + 255) / 256;
  count_pos_kernel<<<CPB, 256, 0, stream>>>(dstv, deg, pos, E);
  scan_partial_kernel<<<NB, 256, 0, stream>>>(deg, inv_s, bsum, gmsum, G * H, N);
  scan_final_kernel<<<NB, 256, 0, stream>>>(deg, bsum, row_off, NB, N);

  int FB = ((E + 3) / 4 + 255) / 256;
  int UXDW = N * (F / 4);
  int TW = F * H + 3 * H * H;
  int PREPB = (UXDW + TW + 255) / 256;
  fill_prep_kernel<<<FB + PREPB, 256, 0, stream>>>(srcv, dstv, pos, row_off, col, E, FB, x,
                                                   inv_s, (unsigned*)u_x, UXDW, W0, Ws, Wt0,
                                                   WtS);

  int AGG0_GRID = (N + 31) / 32;
  int AGG_NS_GRID = ((N + 31) / 32) * 2;  // node-blocks x 2 slices
  int GEMM_GRID = (N + 127) / 128;

  // layer 0: ns agg(u_x fp8) -> fp8 GEMM K=128 (no relu) -> uA
  aggregate_fp8_ns128_kernel<<<AGG0_GRID, 256, 0, stream>>>(u_x, row_off, col, inv_s, aggA, N);
  gemm_kernel<128, false, 1><<<GEMM_GRID, 512, 0, stream>>>(aggA, Wt0, b0, inv_s, batch, gh,
                                                            uA, N);
  // layers 1..2: sliced ns agg(uA fp8) -> fp8 GEMM relu -> uA fp8
  for (int l = 0; l < 2; ++l) {
    aggregate_fp8_ns_kernel<<<AGG_NS_GRID, 256, 0, stream>>>(uA, row_off, col, inv_s, aggA, N);
    gemm_kernel<256, true, 1><<<GEMM_GRID, 512, 0, stream>>>(
        aggA, WtS + (size_t)l * H * H, bs + (size_t)l * H, inv_s, batch, gh, uA, N);
  }
  // layer 3: sliced ns agg -> fp8 GEMM relu + fused mean-pool
  aggregate_fp8_ns_kernel<<<AGG_NS_GRID, 256, 0, stream>>>(uA, row_off, col, inv_s, aggA, N);
  gemm_kernel<256, true, 2><<<GEMM_GRID, 512, 0, stream>>>(
      aggA, WtS + (size_t)2 * H * H, bs + (size_t)2 * H, inv_s, batch, gh, gmsum, N);

  final_kernel<<<G, 256, 0, stream>>>(gmsum, batch, N, gh, Wlin, blin, out,
                                      out + (size_t)G * C, G);
}